// Round 1
// baseline (474.322 us; speedup 1.0000x reference)
//
#include <hip/hip_runtime.h>
#include <math.h>

#define NTOK 131072
#define KC   1024
#define DIMV 64

#define OUT_LOSS 0
#define OUT_Q    1
#define OUT_PERP (1 + NTOK * DIMV)
#define OUT_IDX  (2 + NTOK * DIMV)

// numpy pairwise_sum mimic for n=64 of v[i]*v[i]:
// r[0..7] = a[0..7]; for i=8..56 step 8: r[j] += a[i+j];
// res = ((r0+r1)+(r2+r3))+((r4+r5)+(r6+r7))
// contract(off): numpy squares elementwise (rounded) then adds -- no FMA.
__device__ __forceinline__ float sumsq64_np(const float v[DIMV]) {
#pragma clang fp contract(off)
  {
    float r[8];
#pragma unroll
    for (int j = 0; j < 8; ++j) r[j] = v[j] * v[j];
#pragma unroll
    for (int i = 8; i < 64; i += 8) {
#pragma unroll
      for (int j = 0; j < 8; ++j) r[j] += v[i + j] * v[i + j];
    }
    return ((r[0] + r[1]) + (r[2] + r[3])) + ((r[4] + r[5]) + (r[6] + r[7]));
  }
}

__global__ void __launch_bounds__(256)
vq_main_kernel(const float* __restrict__ xin, const float* __restrict__ cb,
               float* __restrict__ out, float* __restrict__ ws_mse,
               unsigned int* __restrict__ ws_hist) {
  __shared__ float s_norm[KC];
  __shared__ unsigned int s_hist[KC];
  __shared__ float s_red[256];
  const int tid = threadIdx.x;

  // Codebook norms |e_k|^2 (numpy order) into LDS; also zero LDS histogram.
  for (int k = tid; k < KC; k += 256) {
    float e[DIMV];
    const float4* e4 = reinterpret_cast<const float4*>(cb + k * DIMV);
#pragma unroll
    for (int i = 0; i < 16; ++i) {
      float4 t = e4[i];
      e[4 * i + 0] = t.x; e[4 * i + 1] = t.y;
      e[4 * i + 2] = t.z; e[4 * i + 3] = t.w;
    }
    s_norm[k] = sumsq64_np(e);
    s_hist[k] = 0u;
  }
  __syncthreads();

  const int token = blockIdx.x * 256 + tid;

  // Token row into registers (64 VGPRs).
  float x[DIMV];
  const float4* x4 = reinterpret_cast<const float4*>(xin + (long)token * DIMV);
#pragma unroll
  for (int i = 0; i < 16; ++i) {
    float4 t = x4[i];
    x[4 * i + 0] = t.x; x[4 * i + 1] = t.y;
    x[4 * i + 2] = t.z; x[4 * i + 3] = t.w;
  }
  float xx = sumsq64_np(x);

  // Argmin over 1024 codes. cb row address is wave-uniform -> s_load broadcast,
  // inner loop is 64 v_fmac_f32 per code (VALU-bound by design).
  float best = INFINITY;
  int bidx = 0;
#pragma unroll 1
  for (int k = 0; k < KC; ++k) {
    const float* e = cb + k * DIMV;
    float dot = 0.0f;
#pragma unroll
    for (int i = 0; i < DIMV; ++i) dot = __builtin_fmaf(e[i], x[i], dot);
    // mimic reference fp32: (|x|^2 - 2*dot) + |e_k|^2 ; first-occurrence argmin
    float d = (xx - 2.0f * dot) + s_norm[k];
    if (d < best) { best = d; bidx = k; }
  }

  out[OUT_IDX + token] = (float)bidx;
  atomicAdd(&s_hist[bidx], 1u);

  // quantized_st = x + (q - x) in fp32 (mimic), mse partial = sum (q-x)^2
  const float* q = cb + bidx * DIMV;
  float acc = 0.0f;
  float* oq = out + OUT_Q + (long)token * DIMV;
#pragma unroll
  for (int i = 0; i < DIMV; ++i) {
    float qi = q[i];
    float dmx = qi - x[i];    // fl(q - x)
    float qst = x[i] + dmx;   // fl(x + fl(q - x))
    acc = __builtin_fmaf(dmx, dmx, acc);
    oq[i] = qst;
  }

  // Block reduce mse partial; also covers completion of LDS hist atomics.
  s_red[tid] = acc;
  __syncthreads();
#pragma unroll
  for (int s = 128; s > 0; s >>= 1) {
    if (tid < s) s_red[tid] += s_red[tid + s];
    __syncthreads();
  }
  if (tid == 0) atomicAdd(ws_mse, s_red[0]);

  // Flush LDS histogram to global (device-scope atomics).
  for (int k = tid; k < KC; k += 256) {
    unsigned int c = s_hist[k];
    if (c) atomicAdd(&ws_hist[k], c);
  }
}

__global__ void __launch_bounds__(1024)
vq_final_kernel(const unsigned int* __restrict__ ws_hist,
                const float* __restrict__ ws_mse,
                float* __restrict__ out) {
  __shared__ float s_red[1024];
  const int t = threadIdx.x;
  float p = (float)ws_hist[t] / 131072.0f;         // exact (2^17)
  float term = p * logf(p + 1e-10f);               // p==0 -> 0*log(1e-10)=0
  s_red[t] = term;
  __syncthreads();
#pragma unroll
  for (int s = 512; s > 0; s >>= 1) {
    if (t < s) s_red[t] += s_red[t + s];
    __syncthreads();
  }
  if (t == 0) {
    out[OUT_PERP] = expf(-s_red[0]);
    float mse = ws_mse[0] / 8388608.0f;            // exact (2^23)
    out[OUT_LOSS] = mse + 0.25f * mse;
  }
}

extern "C" void kernel_launch(void* const* d_in, const int* in_sizes, int n_in,
                              void* d_out, int out_size, void* d_ws, size_t ws_size,
                              hipStream_t stream) {
  (void)in_sizes; (void)n_in; (void)out_size; (void)ws_size;
  const float* xin = (const float*)d_in[0];
  const float* cb  = (const float*)d_in[1];
  float* out = (float*)d_out;
  float* ws_mse = (float*)d_ws;                 // [0] : mse sum
  unsigned int* ws_hist = (unsigned int*)d_ws + 1;  // [1..1024] : histogram

  hipMemsetAsync(d_ws, 0, sizeof(float) * (1 + KC), stream);
  hipLaunchKernelGGL(vq_main_kernel, dim3(NTOK / 256), dim3(256), 0, stream,
                     xin, cb, out, ws_mse, ws_hist);
  hipLaunchKernelGGL(vq_final_kernel, dim3(1), dim3(1024), 0, stream,
                     ws_hist, ws_mse, out);
}